// Round 4
// baseline (857.360 us; speedup 1.0000x reference)
//
#include <hip/hip_runtime.h>

#define B_   8
#define N_   16384
#define F_   64
#define E_   262144
#define C_   10
#define NF_  (N_ * F_)        // 1048576
#define BN_  (B_ * N_)        // 131072
#define BNF_ (B_ * N_ * F_)   // 8388608
#define BE_  (B_ * E_)        // 2097152
#define CAP_ 48               // padded CSR row capacity; P(Poisson(16) >= 48) ~ 6e-11
#define EPS_ 1e-5f

// ---------------- K1: per-batch LDS-binned count + padded-CSR fill ----------
// One 1024-thread workgroup owns one batch. ZERO global atomics:
//   out-degree counts: LDS, u16 packed 2/word (32 KB)
//   in-degree cursors: LDS, u8 packed 4/word (16 KB)  (cursor == cntI)
// Per edge: 2 LDS atomics + 1 scattered u16 global store.
// Epilogue: plain coalesced stores of rsqrt(deg) + cntI.
__global__ __launch_bounds__(1024) void k_build(
        const int* __restrict__ src, const int* __restrict__ dst,
        float* __restrict__ degOr, float* __restrict__ degIr,
        int* __restrict__ cntI_g, unsigned short* __restrict__ csr) {
    __shared__ unsigned int cntO[N_ / 2];  // 32 KB
    __shared__ unsigned int curI[N_ / 4];  // 16 KB
    int b = blockIdx.x;
    int t = threadIdx.x;
    for (int i = t; i < N_ / 2; i += 1024) cntO[i] = 0;
    for (int i = t; i < N_ / 4; i += 1024) curI[i] = 0;
    __syncthreads();
    const int* sb = src + (size_t)b * E_;
    const int* db = dst + (size_t)b * E_;
    unsigned short* cb = csr + (size_t)b * N_ * CAP_;
    for (int i = t; i < E_; i += 1024) {
        int s = sb[i], d = db[i];
        atomicAdd(&cntO[s >> 1], 1u << ((s & 1) * 16));
        unsigned int old = atomicAdd(&curI[d >> 2], 1u << ((d & 3) * 8));
        unsigned int pos = (old >> ((d & 3) * 8)) & 0xFFu;
        if (pos < CAP_) cb[d * CAP_ + pos] = (unsigned short)s;
    }
    __syncthreads();
    for (int i = t; i < N_; i += 1024) {
        unsigned int co = (cntO[i >> 1] >> ((i & 1) * 16)) & 0xFFFFu;
        unsigned int ci = (curI[i >> 2] >> ((i & 3) * 8)) & 0xFFu;
        degOr[b * N_ + i]  = rsqrtf(fmaxf((float)co, 1.0f));
        degIr[b * N_ + i]  = rsqrtf(fmaxf((float)ci, 1.0f));
        cntI_g[b * N_ + i] = (int)ci;
    }
}

// ---------------- K2: gather: agg[r] = sum_{e in row r} pre(src)*xs[src] ----
// One wave per dst row; lane = feature. XCD swizzle (batch = blockIdx&7)
// localizes the 4 MB batch slice of xs in one XCD's L2.
// PRE: fold the degOr[src] pre-scale (conv1 reads raw x).
template <bool PRE>
__global__ void k_gather(const int* __restrict__ cnt, const unsigned short* __restrict__ csr,
                         const float* __restrict__ xs, const float* __restrict__ degOr,
                         float* __restrict__ agg) {
    int lane = threadIdx.x & 63;
    int wave = threadIdx.x >> 6;
    int b = blockIdx.x & 7;
    int row = (blockIdx.x >> 3) * 4 + wave;
    int wid = b * N_ + row;
    const float* xb = xs + (size_t)b * NF_;
    int n = cnt[wid];
    if (n > CAP_) n = CAP_;
    int sv = (lane < CAP_) ? (int)csr[(size_t)wid * CAP_ + lane] : 0;
    float dv = 0.0f;
    if (PRE) dv = (lane < CAP_) ? degOr[b * N_ + sv] : 0.0f;
    float acc = 0.0f;
    for (int j = 0; j < n; j += 4) {
        int s0 = __shfl(sv, j);
        int s1 = __shfl(sv, j + 1);
        int s2 = __shfl(sv, j + 2);
        int s3 = __shfl(sv, j + 3);
        float v0 = xb[s0 * 64 + lane];
        float v1 = 0.0f, v2 = 0.0f, v3 = 0.0f;
        if (j + 1 < n) v1 = xb[s1 * 64 + lane];  // wave-uniform guards
        if (j + 2 < n) v2 = xb[s2 * 64 + lane];
        if (j + 3 < n) v3 = xb[s3 * 64 + lane];
        if (PRE) {
            float w0 = __shfl(dv, j), w1 = __shfl(dv, j + 1);
            float w2 = __shfl(dv, j + 2), w3 = __shfl(dv, j + 3);
            acc = fmaf(v0, w0, acc);
            acc = fmaf(v1, w1, acc);
            acc = fmaf(v2, w2, acc);
            acc = fmaf(v3, w3, acc);
        } else {
            acc += (v0 + v1) + (v2 + v3);
        }
    }
    agg[(size_t)wid * 64 + lane] = acc;
}

// ---------------- K3: out[r] = act((in[r]*preS[r]) @ W + b) * postS[r] ------
template <bool RELU, bool POST>
__global__ void k_mm(const float* __restrict__ in, const float* __restrict__ W,
                     const float* __restrict__ bias,
                     const float* __restrict__ preS, const float* __restrict__ postS,
                     float* __restrict__ out) {
    __shared__ float Wl[64 * 64];
    __shared__ float rows[4 * 64];
    int t = threadIdx.x;
    for (int i = t; i < 4096; i += 256) Wl[i] = W[i];
    int f = t & 63, rg = t >> 6;
    int rowBase = blockIdx.x * 16;
    for (int it = 0; it < 4; ++it) {
        int r = rowBase + it * 4 + rg;
        __syncthreads();
        rows[rg * 64 + f] = in[r * 64 + f] * preS[r];
        __syncthreads();
        float acc = bias[f];
#pragma unroll
        for (int k = 0; k < 64; ++k) acc = fmaf(rows[rg * 64 + k], Wl[k * 64 + f], acc);
        if (RELU) acc = fmaxf(acc, 0.0f);
        if (POST) acc *= postS[r];
        out[r * 64 + f] = acc;
    }
}

// ---------------- K4: per-channel sum / sumsq -------------------------------
__global__ void k_stats(const float* __restrict__ h, float* __restrict__ stats) {
    int t = threadIdx.x;
    int f = t & 63;
    float s = 0.0f, sq = 0.0f;
    for (int i = blockIdx.x * blockDim.x + t; i < BNF_; i += gridDim.x * blockDim.x) {
        float v = h[i];
        s += v;
        sq += v * v;
    }
    __shared__ float ls[256], lq[256];
    ls[t] = s;
    lq[t] = sq;
    __syncthreads();
    if (t < 64) {
        s  = ls[t] + ls[t + 64] + ls[t + 128] + ls[t + 192];
        sq = lq[t] + lq[t + 64] + lq[t + 128] + lq[t + 192];
        atomicAdd(&stats[f], s);
        atomicAdd(&stats[64 + f], sq);
    }
}

// ---------------- K5: BN scale/shift per channel ----------------------------
__global__ void k_bnfin(const float* __restrict__ stats, const float* __restrict__ gamma,
                        const float* __restrict__ beta, float* __restrict__ sc,
                        float* __restrict__ sh) {
    int f = threadIdx.x;
    if (f < 64) {
        float inv = 1.0f / (float)BN_;
        float mean = stats[f] * inv;
        float var  = stats[64 + f] * inv - mean * mean;
        float s = gamma[f] * rsqrtf(var + EPS_);
        sc[f] = s;
        sh[f] = beta[f] - mean * s;
    }
}

// ---------------- K6: fused BN-apply + final linear -------------------------
__global__ void k_final(const float* __restrict__ h, const float* __restrict__ linW,
                        const float* __restrict__ linb, const float* __restrict__ sc,
                        const float* __restrict__ sh, float* __restrict__ out) {
    int t = threadIdx.x;
    int base = blockIdx.x * (NF_ / 256);  // 4096 per block
    int f = (base + t) & 63;
    float s = sc[f], shv = sh[f];
    float acc[C_ * B_];
#pragma unroll
    for (int j = 0; j < C_ * B_; ++j) acc[j] = 0.0f;

    for (int k = 0; k < 16; ++k) {
        int i = base + k * 256 + t;
        float hv[B_];
#pragma unroll
        for (int b = 0; b < B_; ++b) hv[b] = fmaf(h[b * NF_ + i], s, shv);
#pragma unroll
        for (int c = 0; c < C_; ++c) {
            float w = linW[c * NF_ + i];
#pragma unroll
            for (int b = 0; b < B_; ++b) acc[c * B_ + b] = fmaf(hv[b], w, acc[c * B_ + b]);
        }
    }

    __shared__ float red[4][C_ * B_];
    int lane = t & 63, wv = t >> 6;
#pragma unroll
    for (int j = 0; j < C_ * B_; ++j) {
        float v = acc[j];
        v += __shfl_down(v, 32);
        v += __shfl_down(v, 16);
        v += __shfl_down(v, 8);
        v += __shfl_down(v, 4);
        v += __shfl_down(v, 2);
        v += __shfl_down(v, 1);
        if (lane == 0) red[wv][j] = v;
    }
    __syncthreads();
    if (t < C_ * B_) {
        float v = red[0][t] + red[1][t] + red[2][t] + red[3][t];
        int c = t / B_, b = t % B_;
        if (blockIdx.x == 0) v += linb[c];
        atomicAdd(&out[b * C_ + c], v);
    }
}

extern "C" void kernel_launch(void* const* d_in, const int* in_sizes, int n_in,
                              void* d_out, int out_size, void* d_ws, size_t ws_size,
                              hipStream_t stream) {
    const float* x        = (const float*)d_in[0];
    const int*   edge_src = (const int*)d_in[1];
    const int*   edge_dst = (const int*)d_in[2];
    const float* W1       = (const float*)d_in[3];
    const float* b1       = (const float*)d_in[4];
    const float* W2       = (const float*)d_in[5];
    const float* b2       = (const float*)d_in[6];
    const float* gamma    = (const float*)d_in[7];
    const float* beta     = (const float*)d_in[8];
    const float* linW     = (const float*)d_in[9];
    const float* linb     = (const float*)d_in[10];
    float* out = (float*)d_out;

    char* w = (char*)d_ws;
    float* degOr = (float*)w;           w += BN_ * 4;
    float* degIr = (float*)w;           w += BN_ * 4;
    int*   cntI  = (int*)w;             w += BN_ * 4;
    unsigned short* csr = (unsigned short*)w; w += (size_t)BN_ * CAP_ * 2;
    float* bufA  = (float*)w;           w += (size_t)BNF_ * 4;
    float* bufB  = (float*)w;           w += (size_t)BNF_ * 4;
    float* stats = (float*)w;           w += 128 * 4;
    float* sc    = (float*)w;           w += 64 * 4;
    float* sh    = (float*)w;           w += 64 * 4;

    hipMemsetAsync(stats, 0, 128 * sizeof(float), stream);
    hipMemsetAsync(out, 0, B_ * C_ * sizeof(float), stream);

    // CSR build + degrees (once, reused by both convs) — zero global atomics
    k_build<<<B_, 1024, 0, stream>>>(edge_src, edge_dst, degOr, degIr, cntI, csr);

    // conv1: gather folds degOr[src] pre-scale; mm folds degIr pre + degOr post
    k_gather<true><<<BN_ / 4, 256, 0, stream>>>(cntI, csr, x, degOr, bufB);
    k_mm<true, true><<<BN_ / 16, 256, 0, stream>>>(bufB, W1, b1, degIr, degOr, bufA);

    // conv2
    k_gather<false><<<BN_ / 4, 256, 0, stream>>>(cntI, csr, bufA, degOr, bufB);
    k_mm<false, false><<<BN_ / 16, 256, 0, stream>>>(bufB, W2, b2, degIr, degIr, bufA);

    // batchnorm stats + fused BN + final linear
    k_stats<<<256, 256, 0, stream>>>(bufA, stats);
    k_bnfin<<<1, 64, 0, stream>>>(stats, gamma, beta, sc, sh);
    k_final<<<256, 256, 0, stream>>>(bufA, linW, linb, sc, sh, out);
}

// Round 5
// 455.662 us; speedup vs baseline: 1.8816x; 1.8816x over previous
//
#include <hip/hip_runtime.h>

#define B_     8
#define N_     16384
#define F_     64
#define E_     262144
#define C_     10
#define NF_    (N_ * F_)        // 1048576
#define BN_    (B_ * N_)        // 131072
#define BNF_   (B_ * N_ * F_)   // 8388608
#define BE_    (B_ * E_)        // 2097152
#define CAP_   48               // padded CSR row capacity; P(Poisson(16) >= 48) ~ 6e-11
#define CHUNK_ 4096             // edges per build workgroup
#define NCH_   (E_ / CHUNK_)    // 64 chunks per batch
#define NW_    (N_ / 4)         // 4096 packed-u8 words per batch
#define EPS_   1e-5f

// ---------------- Build phase A: per-chunk privatized counts ----------------
// 512 WGs (8 batches x 64 chunks). Counts src/dst of a 4096-edge chunk into
// packed-u8 LDS bins (per-chunk per-row count <= ~10 << 255), then writes
// partials coalesced. Zero global atomics.
__global__ __launch_bounds__(256) void k_count(const int* __restrict__ src,
                                               const int* __restrict__ dst,
                                               unsigned int* __restrict__ partO,
                                               unsigned int* __restrict__ partI) {
    __shared__ unsigned int pO[NW_];  // 16 KB
    __shared__ unsigned int pI[NW_];  // 16 KB
    int t = threadIdx.x;
    int b = blockIdx.x & 7, c = blockIdx.x >> 3;
    for (int i = t; i < NW_; i += 256) { pO[i] = 0; pI[i] = 0; }
    __syncthreads();
    const int* sb = src + (size_t)b * E_ + (size_t)c * CHUNK_;
    const int* db = dst + (size_t)b * E_ + (size_t)c * CHUNK_;
    for (int i = t; i < CHUNK_; i += 256) {
        int s = sb[i], d = db[i];
        atomicAdd(&pO[s >> 2], 1u << ((s & 3) * 8));
        atomicAdd(&pI[d >> 2], 1u << ((d & 3) * 8));
    }
    __syncthreads();
    size_t base = (size_t)(b * NCH_ + c) * NW_;
    for (int i = t; i < NW_; i += 256) {
        partO[base + i] = pO[i];
        partI[base + i] = pI[i];
    }
}

// ---------------- Build phase B: packed prefix over chunks + degrees --------
// One thread owns 4 rows (one packed word). Byte-lane packed adds are safe:
// per-row totals <= ~48 < 255. Lane-coalesced loads (consecutive rw per lane).
__global__ __launch_bounds__(256) void k_offsets(const unsigned int* __restrict__ partO,
                                                 const unsigned int* __restrict__ partI,
                                                 unsigned int* __restrict__ baseArr,
                                                 float* __restrict__ degOr,
                                                 float* __restrict__ degIr,
                                                 int* __restrict__ cntI_g) {
    int gw = blockIdx.x * 256 + threadIdx.x;  // word id in [0, BN_/4)
    int b = gw >> 12;                         // 4096 words per batch
    int rw = gw & 4095;
    unsigned int sumI = 0, sumO = 0;
    for (int c = 0; c < NCH_; ++c) {
        size_t idx = (size_t)(b * NCH_ + c) * NW_ + rw;
        unsigned int wI = partI[idx];
        baseArr[idx] = sumI;  // exclusive prefix, packed u8 lanes
        sumI += wI;
        sumO += partO[idx];
    }
    int row0 = gw * 4;  // == b*N_ + rw*4
#pragma unroll
    for (int r = 0; r < 4; ++r) {
        unsigned int ci = (sumI >> (r * 8)) & 0xFFu;
        unsigned int co = (sumO >> (r * 8)) & 0xFFu;
        degIr[row0 + r] = rsqrtf(fmaxf((float)ci, 1.0f));
        degOr[row0 + r] = rsqrtf(fmaxf((float)co, 1.0f));
        cntI_g[row0 + r] = (int)ci;
    }
}

// ---------------- Build phase C: deterministic-offset CSR fill --------------
// Re-reads the chunk, recomputes within-chunk cursors in LDS, places each
// edge at row*CAP + base[chunk][row] + cursor. 1 LDS atomic + 1 u16 store
// per edge; u16 scatters are L2-absorbed (R4: WRITE_SIZE ~8 MB).
__global__ __launch_bounds__(256) void k_fill(const int* __restrict__ src,
                                              const int* __restrict__ dst,
                                              const unsigned int* __restrict__ baseArr,
                                              unsigned short* __restrict__ csr) {
    __shared__ unsigned int cur[NW_];  // 16 KB
    __shared__ unsigned int bw[NW_];   // 16 KB
    int t = threadIdx.x;
    int b = blockIdx.x & 7, c = blockIdx.x >> 3;
    size_t pbase = (size_t)(b * NCH_ + c) * NW_;
    for (int i = t; i < NW_; i += 256) { cur[i] = 0; bw[i] = baseArr[pbase + i]; }
    __syncthreads();
    const int* sb = src + (size_t)b * E_ + (size_t)c * CHUNK_;
    const int* db = dst + (size_t)b * E_ + (size_t)c * CHUNK_;
    unsigned short* cb = csr + (size_t)b * N_ * CAP_;
    for (int i = t; i < CHUNK_; i += 256) {
        int s = sb[i], d = db[i];
        unsigned int sh = (d & 3) * 8;
        unsigned int old = atomicAdd(&cur[d >> 2], 1u << sh);
        unsigned int pos = ((old >> sh) & 0xFFu) + ((bw[d >> 2] >> sh) & 0xFFu);
        if (pos < CAP_) cb[d * CAP_ + pos] = (unsigned short)s;
    }
}

// ---------------- Gather: agg[r] = sum_{e in row r} pre(src)*xs[src] --------
// One wave per dst row; lane = feature. XCD swizzle (batch = blockIdx&7).
// PRE: fold the degOr[src] pre-scale (conv1 reads raw x).
template <bool PRE>
__global__ void k_gather(const int* __restrict__ cnt, const unsigned short* __restrict__ csr,
                         const float* __restrict__ xs, const float* __restrict__ degOr,
                         float* __restrict__ agg) {
    int lane = threadIdx.x & 63;
    int wave = threadIdx.x >> 6;
    int b = blockIdx.x & 7;
    int row = (blockIdx.x >> 3) * 4 + wave;
    int wid = b * N_ + row;
    const float* xb = xs + (size_t)b * NF_;
    int n = cnt[wid];
    if (n > CAP_) n = CAP_;
    int sv = (lane < CAP_) ? (int)csr[(size_t)wid * CAP_ + lane] : 0;
    float dv = 0.0f;
    if (PRE) dv = (lane < CAP_) ? degOr[b * N_ + sv] : 0.0f;
    float acc = 0.0f;
    for (int j = 0; j < n; j += 4) {
        int s0 = __shfl(sv, j);
        int s1 = __shfl(sv, j + 1);
        int s2 = __shfl(sv, j + 2);
        int s3 = __shfl(sv, j + 3);
        float v0 = xb[s0 * 64 + lane];
        float v1 = 0.0f, v2 = 0.0f, v3 = 0.0f;
        if (j + 1 < n) v1 = xb[s1 * 64 + lane];  // wave-uniform guards
        if (j + 2 < n) v2 = xb[s2 * 64 + lane];
        if (j + 3 < n) v3 = xb[s3 * 64 + lane];
        if (PRE) {
            float w0 = __shfl(dv, j), w1 = __shfl(dv, j + 1);
            float w2 = __shfl(dv, j + 2), w3 = __shfl(dv, j + 3);
            acc = fmaf(v0, w0, acc);
            acc = fmaf(v1, w1, acc);
            acc = fmaf(v2, w2, acc);
            acc = fmaf(v3, w3, acc);
        } else {
            acc += (v0 + v1) + (v2 + v3);
        }
    }
    agg[(size_t)wid * 64 + lane] = acc;
}

// ---------------- out[r] = act((in[r]*preS[r]) @ W + b) * postS[r] ----------
template <bool RELU, bool POST>
__global__ void k_mm(const float* __restrict__ in, const float* __restrict__ W,
                     const float* __restrict__ bias,
                     const float* __restrict__ preS, const float* __restrict__ postS,
                     float* __restrict__ out) {
    __shared__ float Wl[64 * 64];
    __shared__ float rows[4 * 64];
    int t = threadIdx.x;
    for (int i = t; i < 4096; i += 256) Wl[i] = W[i];
    int f = t & 63, rg = t >> 6;
    int rowBase = blockIdx.x * 16;
    for (int it = 0; it < 4; ++it) {
        int r = rowBase + it * 4 + rg;
        __syncthreads();
        rows[rg * 64 + f] = in[r * 64 + f] * preS[r];
        __syncthreads();
        float acc = bias[f];
#pragma unroll
        for (int k = 0; k < 64; ++k) acc = fmaf(rows[rg * 64 + k], Wl[k * 64 + f], acc);
        if (RELU) acc = fmaxf(acc, 0.0f);
        if (POST) acc *= postS[r];
        out[r * 64 + f] = acc;
    }
}

// ---------------- per-channel sum / sumsq -----------------------------------
__global__ void k_stats(const float* __restrict__ h, float* __restrict__ stats) {
    int t = threadIdx.x;
    int f = t & 63;
    float s = 0.0f, sq = 0.0f;
    for (int i = blockIdx.x * blockDim.x + t; i < BNF_; i += gridDim.x * blockDim.x) {
        float v = h[i];
        s += v;
        sq += v * v;
    }
    __shared__ float ls[256], lq[256];
    ls[t] = s;
    lq[t] = sq;
    __syncthreads();
    if (t < 64) {
        s  = ls[t] + ls[t + 64] + ls[t + 128] + ls[t + 192];
        sq = lq[t] + lq[t + 64] + lq[t + 128] + lq[t + 192];
        atomicAdd(&stats[f], s);
        atomicAdd(&stats[64 + f], sq);
    }
}

// ---------------- BN scale/shift per channel --------------------------------
__global__ void k_bnfin(const float* __restrict__ stats, const float* __restrict__ gamma,
                        const float* __restrict__ beta, float* __restrict__ sc,
                        float* __restrict__ sh) {
    int f = threadIdx.x;
    if (f < 64) {
        float inv = 1.0f / (float)BN_;
        float mean = stats[f] * inv;
        float var  = stats[64 + f] * inv - mean * mean;
        float s = gamma[f] * rsqrtf(var + EPS_);
        sc[f] = s;
        sh[f] = beta[f] - mean * s;
    }
}

// ---------------- fused BN-apply + final linear -----------------------------
__global__ void k_final(const float* __restrict__ h, const float* __restrict__ linW,
                        const float* __restrict__ linb, const float* __restrict__ sc,
                        const float* __restrict__ sh, float* __restrict__ out) {
    int t = threadIdx.x;
    int base = blockIdx.x * (NF_ / 256);  // 4096 per block
    int f = (base + t) & 63;
    float s = sc[f], shv = sh[f];
    float acc[C_ * B_];
#pragma unroll
    for (int j = 0; j < C_ * B_; ++j) acc[j] = 0.0f;

    for (int k = 0; k < 16; ++k) {
        int i = base + k * 256 + t;
        float hv[B_];
#pragma unroll
        for (int b = 0; b < B_; ++b) hv[b] = fmaf(h[b * NF_ + i], s, shv);
#pragma unroll
        for (int c = 0; c < C_; ++c) {
            float w = linW[c * NF_ + i];
#pragma unroll
            for (int b = 0; b < B_; ++b) acc[c * B_ + b] = fmaf(hv[b], w, acc[c * B_ + b]);
        }
    }

    __shared__ float red[4][C_ * B_];
    int lane = t & 63, wv = t >> 6;
#pragma unroll
    for (int j = 0; j < C_ * B_; ++j) {
        float v = acc[j];
        v += __shfl_down(v, 32);
        v += __shfl_down(v, 16);
        v += __shfl_down(v, 8);
        v += __shfl_down(v, 4);
        v += __shfl_down(v, 2);
        v += __shfl_down(v, 1);
        if (lane == 0) red[wv][j] = v;
    }
    __syncthreads();
    if (t < C_ * B_) {
        float v = red[0][t] + red[1][t] + red[2][t] + red[3][t];
        int c = t / B_, b = t % B_;
        if (blockIdx.x == 0) v += linb[c];
        atomicAdd(&out[b * C_ + c], v);
    }
}

extern "C" void kernel_launch(void* const* d_in, const int* in_sizes, int n_in,
                              void* d_out, int out_size, void* d_ws, size_t ws_size,
                              hipStream_t stream) {
    const float* x        = (const float*)d_in[0];
    const int*   edge_src = (const int*)d_in[1];
    const int*   edge_dst = (const int*)d_in[2];
    const float* W1       = (const float*)d_in[3];
    const float* b1       = (const float*)d_in[4];
    const float* W2       = (const float*)d_in[5];
    const float* b2       = (const float*)d_in[6];
    const float* gamma    = (const float*)d_in[7];
    const float* beta     = (const float*)d_in[8];
    const float* linW     = (const float*)d_in[9];
    const float* linb     = (const float*)d_in[10];
    float* out = (float*)d_out;

    char* w = (char*)d_ws;
    float* degOr = (float*)w;           w += BN_ * 4;
    float* degIr = (float*)w;           w += BN_ * 4;
    int*   cntI  = (int*)w;             w += BN_ * 4;
    unsigned short* csr = (unsigned short*)w; w += (size_t)BN_ * CAP_ * 2;
    float* bufA  = (float*)w;           w += (size_t)BNF_ * 4;
    float* bufB  = (float*)w;           w += (size_t)BNF_ * 4;
    float* stats = (float*)w;           w += 128 * 4;
    float* sc    = (float*)w;           w += 64 * 4;
    float* sh    = (float*)w;           w += 64 * 4;

    // Build scratch aliases bufA/bufB (dead until gather1/mm1 write them):
    unsigned int* partO   = (unsigned int*)bufA;                  // 8 MB
    unsigned int* partI   = partO + (size_t)B_ * NCH_ * NW_;      // 8 MB
    unsigned int* baseArr = (unsigned int*)bufB;                  // 8 MB

    hipMemsetAsync(stats, 0, 128 * sizeof(float), stream);
    hipMemsetAsync(out, 0, B_ * C_ * sizeof(float), stream);

    // CSR build + degrees: two-phase privatized, zero global atomics
    k_count<<<B_ * NCH_, 256, 0, stream>>>(edge_src, edge_dst, partO, partI);
    k_offsets<<<BN_ / 4 / 256, 256, 0, stream>>>(partO, partI, baseArr, degOr, degIr, cntI);
    k_fill<<<B_ * NCH_, 256, 0, stream>>>(edge_src, edge_dst, baseArr, csr);

    // conv1: gather folds degOr[src] pre-scale; mm folds degIr pre + degOr post
    k_gather<true><<<BN_ / 4, 256, 0, stream>>>(cntI, csr, x, degOr, bufB);
    k_mm<true, true><<<BN_ / 16, 256, 0, stream>>>(bufB, W1, b1, degIr, degOr, bufA);

    // conv2
    k_gather<false><<<BN_ / 4, 256, 0, stream>>>(cntI, csr, bufA, degOr, bufB);
    k_mm<false, false><<<BN_ / 16, 256, 0, stream>>>(bufB, W2, b2, degIr, degIr, bufA);

    // batchnorm stats + fused BN + final linear
    k_stats<<<256, 256, 0, stream>>>(bufA, stats);
    k_bnfin<<<1, 64, 0, stream>>>(stats, gamma, beta, sc, sh);
    k_final<<<256, 256, 0, stream>>>(bufA, linW, linb, sc, sh, out);
}

// Round 6
// 357.973 us; speedup vs baseline: 2.3950x; 1.2729x over previous
//
#include <hip/hip_runtime.h>

#define B_     8
#define N_     16384
#define F_     64
#define E_     262144
#define C_     10
#define NF_    (N_ * F_)        // 1048576
#define BN_    (B_ * N_)        // 131072
#define BNF_   (B_ * N_ * F_)   // 8388608
#define BE_    (B_ * E_)        // 2097152
#define CAP_   48               // padded CSR row capacity; P(Poisson(16) >= 48) ~ 6e-11
#define CHUNK_ 4096             // edges per build workgroup
#define NCH_   (E_ / CHUNK_)    // 64 chunks per batch
#define NW_    (N_ / 4)         // 4096 packed-u8 words per batch
#define EPS_   1e-5f

// ---------------- Build phase A: per-chunk privatized counts ----------------
__global__ __launch_bounds__(256) void k_count(const int* __restrict__ src,
                                               const int* __restrict__ dst,
                                               unsigned int* __restrict__ partO,
                                               unsigned int* __restrict__ partI) {
    __shared__ unsigned int pO[NW_];  // 16 KB
    __shared__ unsigned int pI[NW_];  // 16 KB
    int t = threadIdx.x;
    int b = blockIdx.x & 7, c = blockIdx.x >> 3;
    for (int i = t; i < NW_; i += 256) { pO[i] = 0; pI[i] = 0; }
    __syncthreads();
    const int* sb = src + (size_t)b * E_ + (size_t)c * CHUNK_;
    const int* db = dst + (size_t)b * E_ + (size_t)c * CHUNK_;
    for (int i = t; i < CHUNK_; i += 256) {
        int s = sb[i], d = db[i];
        atomicAdd(&pO[s >> 2], 1u << ((s & 3) * 8));
        atomicAdd(&pI[d >> 2], 1u << ((d & 3) * 8));
    }
    __syncthreads();
    size_t base = (size_t)(b * NCH_ + c) * NW_;
    for (int i = t; i < NW_; i += 256) {
        partO[base + i] = pO[i];
        partI[base + i] = pI[i];
    }
}

// ---------------- Build phase B: packed prefix over chunks + degrees --------
__global__ __launch_bounds__(256) void k_offsets(const unsigned int* __restrict__ partO,
                                                 const unsigned int* __restrict__ partI,
                                                 unsigned int* __restrict__ baseArr,
                                                 float* __restrict__ degOr,
                                                 float* __restrict__ degIr,
                                                 int* __restrict__ cntI_g) {
    int gw = blockIdx.x * 256 + threadIdx.x;  // word id in [0, BN_/4)
    int b = gw >> 12;
    int rw = gw & 4095;
    unsigned int sumI = 0, sumO = 0;
    for (int c = 0; c < NCH_; ++c) {
        size_t idx = (size_t)(b * NCH_ + c) * NW_ + rw;
        unsigned int wI = partI[idx];
        baseArr[idx] = sumI;  // exclusive prefix, packed u8 lanes
        sumI += wI;
        sumO += partO[idx];
    }
    int row0 = gw * 4;
#pragma unroll
    for (int r = 0; r < 4; ++r) {
        unsigned int ci = (sumI >> (r * 8)) & 0xFFu;
        unsigned int co = (sumO >> (r * 8)) & 0xFFu;
        degIr[row0 + r] = rsqrtf(fmaxf((float)ci, 1.0f));
        degOr[row0 + r] = rsqrtf(fmaxf((float)co, 1.0f));
        cntI_g[row0 + r] = (int)ci;
    }
}

// ---------------- Build phase C: deterministic-offset CSR fill --------------
__global__ __launch_bounds__(256) void k_fill(const int* __restrict__ src,
                                              const int* __restrict__ dst,
                                              const unsigned int* __restrict__ baseArr,
                                              unsigned short* __restrict__ csr) {
    __shared__ unsigned int cur[NW_];  // 16 KB
    __shared__ unsigned int bw[NW_];   // 16 KB
    int t = threadIdx.x;
    int b = blockIdx.x & 7, c = blockIdx.x >> 3;
    size_t pbase = (size_t)(b * NCH_ + c) * NW_;
    for (int i = t; i < NW_; i += 256) { cur[i] = 0; bw[i] = baseArr[pbase + i]; }
    __syncthreads();
    const int* sb = src + (size_t)b * E_ + (size_t)c * CHUNK_;
    const int* db = dst + (size_t)b * E_ + (size_t)c * CHUNK_;
    unsigned short* cb = csr + (size_t)b * N_ * CAP_;
    for (int i = t; i < CHUNK_; i += 256) {
        int s = sb[i], d = db[i];
        unsigned int sh = (d & 3) * 8;
        unsigned int old = atomicAdd(&cur[d >> 2], 1u << sh);
        unsigned int pos = ((old >> sh) & 0xFFu) + ((bw[d >> 2] >> sh) & 0xFFu);
        if (pos < CAP_) cb[d * CAP_ + pos] = (unsigned short)s;
    }
}

// ---------------- Fused conv: gather + (row @ W + bias) + scalings ----------
// 256 threads = 4 waves; wave handles 4 rows. Lane layout: r = lane>>4 (row),
// c = lane&15 (float4 feature group). One dwordx4 load carries 4 edges (one
// per sub-group). CSR entries for a row live across its 16 lanes in 3 regs;
// broadcast via per-lane-index __shfl. Epilogue multiplies the aggregated row
// (spread over 16 lanes) by LDS-staged W via shfl-broadcast + ds_read_b128.
//   out = act((agg * preR[row]) @ W + bias) * postR[row]
//   PRE: agg = sum_e preE[src_e] * xs[src_e]   (conv1 folds degOr[src])
template <bool PRE, bool RELU, bool POST>
__global__ __launch_bounds__(256) void k_conv(
        const int* __restrict__ cnt, const unsigned short* __restrict__ csr,
        const float* __restrict__ xs, const float* __restrict__ preE,
        const float* __restrict__ preR, const float* __restrict__ postR,
        const float* __restrict__ W, const float* __restrict__ bias,
        float* __restrict__ out) {
    __shared__ float4 Wl[64 * 16];  // 16 KB, [f][c]
    int t = threadIdx.x;
    const float4* Wg = (const float4*)W;
    for (int i = t; i < 1024; i += 256) Wl[i] = Wg[i];
    __syncthreads();

    int lane = t & 63;
    int wave = t >> 6;
    int c = lane & 15;
    int b = blockIdx.x & 7;  // XCD swizzle: one batch per XCD -> L2-resident xs
    int row = (blockIdx.x >> 3) * 16 + wave * 4 + (lane >> 4);
    int wid = b * N_ + row;
    const float* xb = xs + (size_t)b * NF_;
    int lb = lane & 48;
    int co = c * 4;

    int n = cnt[wid];
    if (n > CAP_) n = CAP_;
    size_t cb = (size_t)wid * CAP_;
    int e0 = csr[cb + c] & 0x3FFF;        // mask: entries >= n may be stale
    int e1 = csr[cb + 16 + c] & 0x3FFF;
    int e2 = csr[cb + 32 + c] & 0x3FFF;
    float d0 = 0.0f, d1 = 0.0f, d2 = 0.0f;
    if (PRE) {
        const float* pe = preE + b * N_;
        d0 = pe[e0]; d1 = pe[e1]; d2 = pe[e2];
    }
    int m = n;  // wave-uniform max count across the 4 rows
    m = max(m, __shfl_xor(m, 16));
    m = max(m, __shfl_xor(m, 32));

    float ax = 0.0f, ay = 0.0f, az = 0.0f, aw = 0.0f;

#define SEG(EREG, DREG, BASE)                                                  \
    {                                                                          \
        int lim = m - (BASE); if (lim > 16) lim = 16;                          \
        int rem = n - (BASE); /* per-lane active count in this segment */      \
        for (int jj = 0; jj < lim; jj += 4) {                                  \
            int s0 = __shfl(EREG, lb + jj);                                    \
            int s1 = __shfl(EREG, lb + jj + 1);                                \
            int s2 = __shfl(EREG, lb + jj + 2);                                \
            int s3 = __shfl(EREG, lb + jj + 3);                                \
            float w0 = 1.0f, w1 = 1.0f, w2 = 1.0f, w3 = 1.0f;                  \
            if (PRE) {                                                         \
                w0 = __shfl(DREG, lb + jj);                                    \
                w1 = __shfl(DREG, lb + jj + 1);                                \
                w2 = __shfl(DREG, lb + jj + 2);                                \
                w3 = __shfl(DREG, lb + jj + 3);                                \
            }                                                                  \
            float4 v0 = {0,0,0,0}, v1 = {0,0,0,0}, v2 = {0,0,0,0}, v3 = {0,0,0,0}; \
            if (jj < rem)     v0 = *(const float4*)(xb + s0 * 64 + co);        \
            if (jj + 1 < rem) v1 = *(const float4*)(xb + s1 * 64 + co);        \
            if (jj + 2 < rem) v2 = *(const float4*)(xb + s2 * 64 + co);        \
            if (jj + 3 < rem) v3 = *(const float4*)(xb + s3 * 64 + co);        \
            if (PRE) {                                                         \
                ax = fmaf(v0.x, w0, ax); ay = fmaf(v0.y, w0, ay);              \
                az = fmaf(v0.z, w0, az); aw = fmaf(v0.w, w0, aw);              \
                ax = fmaf(v1.x, w1, ax); ay = fmaf(v1.y, w1, ay);              \
                az = fmaf(v1.z, w1, az); aw = fmaf(v1.w, w1, aw);              \
                ax = fmaf(v2.x, w2, ax); ay = fmaf(v2.y, w2, ay);              \
                az = fmaf(v2.z, w2, az); aw = fmaf(v2.w, w2, aw);              \
                ax = fmaf(v3.x, w3, ax); ay = fmaf(v3.y, w3, ay);              \
                az = fmaf(v3.z, w3, az); aw = fmaf(v3.w, w3, aw);              \
            } else {                                                           \
                ax += (v0.x + v1.x) + (v2.x + v3.x);                           \
                ay += (v0.y + v1.y) + (v2.y + v3.y);                           \
                az += (v0.z + v1.z) + (v2.z + v3.z);                           \
                aw += (v0.w + v1.w) + (v2.w + v3.w);                           \
            }                                                                  \
        }                                                                      \
    }

    SEG(e0, d0, 0)
    if (m > 16) SEG(e1, d1, 16)
    if (m > 32) SEG(e2, d2, 32)
#undef SEG

    // epilogue: row pre-scale, @W, bias, act, post-scale, store
    float pre = preR[wid];
    ax *= pre; ay *= pre; az *= pre; aw *= pre;
    const float4 bv = ((const float4*)bias)[c];
    float ox = bv.x, oy = bv.y, oz = bv.z, ow = bv.w;
#pragma unroll
    for (int fg = 0; fg < 16; ++fg) {
        int sl = lb + fg;
        float a0 = __shfl(ax, sl);
        float a1 = __shfl(ay, sl);
        float a2 = __shfl(az, sl);
        float a3 = __shfl(aw, sl);
        float4 w0 = Wl[(fg * 4 + 0) * 16 + c];
        float4 w1 = Wl[(fg * 4 + 1) * 16 + c];
        float4 w2 = Wl[(fg * 4 + 2) * 16 + c];
        float4 w3 = Wl[(fg * 4 + 3) * 16 + c];
        ox = fmaf(a0, w0.x, ox); oy = fmaf(a0, w0.y, oy); oz = fmaf(a0, w0.z, oz); ow = fmaf(a0, w0.w, ow);
        ox = fmaf(a1, w1.x, ox); oy = fmaf(a1, w1.y, oy); oz = fmaf(a1, w1.z, oz); ow = fmaf(a1, w1.w, ow);
        ox = fmaf(a2, w2.x, ox); oy = fmaf(a2, w2.y, oy); oz = fmaf(a2, w2.z, oz); ow = fmaf(a2, w2.w, ow);
        ox = fmaf(a3, w3.x, ox); oy = fmaf(a3, w3.y, oy); oz = fmaf(a3, w3.z, oz); ow = fmaf(a3, w3.w, ow);
    }
    if (RELU) {
        ox = fmaxf(ox, 0.0f); oy = fmaxf(oy, 0.0f);
        oz = fmaxf(oz, 0.0f); ow = fmaxf(ow, 0.0f);
    }
    if (POST) {
        float p = postR[wid];
        ox *= p; oy *= p; oz *= p; ow *= p;
    }
    float4 o; o.x = ox; o.y = oy; o.z = oz; o.w = ow;
    *(float4*)(out + (size_t)wid * 64 + co) = o;
}

// ---------------- per-channel sum / sumsq -----------------------------------
__global__ void k_stats(const float* __restrict__ h, float* __restrict__ stats) {
    int t = threadIdx.x;
    int f = t & 63;
    float s = 0.0f, sq = 0.0f;
    for (int i = blockIdx.x * blockDim.x + t; i < BNF_; i += gridDim.x * blockDim.x) {
        float v = h[i];
        s += v;
        sq += v * v;
    }
    __shared__ float ls[256], lq[256];
    ls[t] = s;
    lq[t] = sq;
    __syncthreads();
    if (t < 64) {
        s  = ls[t] + ls[t + 64] + ls[t + 128] + ls[t + 192];
        sq = lq[t] + lq[t + 64] + lq[t + 128] + lq[t + 192];
        atomicAdd(&stats[f], s);
        atomicAdd(&stats[64 + f], sq);
    }
}

// ---------------- BN scale/shift per channel --------------------------------
__global__ void k_bnfin(const float* __restrict__ stats, const float* __restrict__ gamma,
                        const float* __restrict__ beta, float* __restrict__ sc,
                        float* __restrict__ sh) {
    int f = threadIdx.x;
    if (f < 64) {
        float inv = 1.0f / (float)BN_;
        float mean = stats[f] * inv;
        float var  = stats[64 + f] * inv - mean * mean;
        float s = gamma[f] * rsqrtf(var + EPS_);
        sc[f] = s;
        sh[f] = beta[f] - mean * s;
    }
}

// ---------------- fused BN-apply + final linear -----------------------------
__global__ void k_final(const float* __restrict__ h, const float* __restrict__ linW,
                        const float* __restrict__ linb, const float* __restrict__ sc,
                        const float* __restrict__ sh, float* __restrict__ out) {
    int t = threadIdx.x;
    int base = blockIdx.x * (NF_ / 256);  // 4096 per block
    int f = (base + t) & 63;
    float s = sc[f], shv = sh[f];
    float acc[C_ * B_];
#pragma unroll
    for (int j = 0; j < C_ * B_; ++j) acc[j] = 0.0f;

    for (int k = 0; k < 16; ++k) {
        int i = base + k * 256 + t;
        float hv[B_];
#pragma unroll
        for (int b = 0; b < B_; ++b) hv[b] = fmaf(h[b * NF_ + i], s, shv);
#pragma unroll
        for (int c = 0; c < C_; ++c) {
            float w = linW[c * NF_ + i];
#pragma unroll
            for (int b = 0; b < B_; ++b) acc[c * B_ + b] = fmaf(hv[b], w, acc[c * B_ + b]);
        }
    }

    __shared__ float red[4][C_ * B_];
    int lane = t & 63, wv = t >> 6;
#pragma unroll
    for (int j = 0; j < C_ * B_; ++j) {
        float v = acc[j];
        v += __shfl_down(v, 32);
        v += __shfl_down(v, 16);
        v += __shfl_down(v, 8);
        v += __shfl_down(v, 4);
        v += __shfl_down(v, 2);
        v += __shfl_down(v, 1);
        if (lane == 0) red[wv][j] = v;
    }
    __syncthreads();
    if (t < C_ * B_) {
        float v = red[0][t] + red[1][t] + red[2][t] + red[3][t];
        int c = t / B_, b = t % B_;
        if (blockIdx.x == 0) v += linb[c];
        atomicAdd(&out[b * C_ + c], v);
    }
}

extern "C" void kernel_launch(void* const* d_in, const int* in_sizes, int n_in,
                              void* d_out, int out_size, void* d_ws, size_t ws_size,
                              hipStream_t stream) {
    const float* x        = (const float*)d_in[0];
    const int*   edge_src = (const int*)d_in[1];
    const int*   edge_dst = (const int*)d_in[2];
    const float* W1       = (const float*)d_in[3];
    const float* b1       = (const float*)d_in[4];
    const float* W2       = (const float*)d_in[5];
    const float* b2       = (const float*)d_in[6];
    const float* gamma    = (const float*)d_in[7];
    const float* beta     = (const float*)d_in[8];
    const float* linW     = (const float*)d_in[9];
    const float* linb     = (const float*)d_in[10];
    float* out = (float*)d_out;

    char* w = (char*)d_ws;
    float* degOr = (float*)w;           w += BN_ * 4;
    float* degIr = (float*)w;           w += BN_ * 4;
    int*   cntI  = (int*)w;             w += BN_ * 4;
    unsigned short* csr = (unsigned short*)w; w += (size_t)BN_ * CAP_ * 2;
    float* bufA  = (float*)w;           w += (size_t)BNF_ * 4;
    float* bufB  = (float*)w;           w += (size_t)BNF_ * 4;
    float* stats = (float*)w;           w += 128 * 4;
    float* sc    = (float*)w;           w += 64 * 4;
    float* sh    = (float*)w;           w += 64 * 4;

    // Build scratch aliases bufA/bufB (dead before conv1 writes bufA):
    unsigned int* partO   = (unsigned int*)bufA;
    unsigned int* partI   = partO + (size_t)B_ * NCH_ * NW_;
    unsigned int* baseArr = (unsigned int*)bufB;

    hipMemsetAsync(stats, 0, 128 * sizeof(float), stream);
    hipMemsetAsync(out, 0, B_ * C_ * sizeof(float), stream);

    // CSR build + degrees: two-phase privatized, zero global atomics
    k_count<<<B_ * NCH_, 256, 0, stream>>>(edge_src, edge_dst, partO, partI);
    k_offsets<<<BN_ / 4 / 256, 256, 0, stream>>>(partO, partI, baseArr, degOr, degIr, cntI);
    k_fill<<<B_ * NCH_, 256, 0, stream>>>(edge_src, edge_dst, baseArr, csr);

    // conv1: h1 = relu((sum degOr[s]*x[s]) * degIr @ W1 + b1) * degOr -> bufA
    k_conv<true, true, true><<<BN_ / 16, 256, 0, stream>>>(
        cntI, csr, x, degOr, degIr, degOr, W1, b1, bufA);

    // conv2: h2 = ((sum h1[s]) * degIr) @ W2 + b2 -> bufB
    k_conv<false, false, false><<<BN_ / 16, 256, 0, stream>>>(
        cntI, csr, bufA, degOr, degIr, degIr, W2, b2, bufB);

    // batchnorm stats + fused BN + final linear
    k_stats<<<256, 256, 0, stream>>>(bufB, stats);
    k_bnfin<<<1, 64, 0, stream>>>(stats, gamma, beta, sc, sh);
    k_final<<<256, 256, 0, stream>>>(bufB, linW, linb, sc, sh, out);
}